// Round 1
// baseline (341.642 us; speedup 1.0000x reference)
//
#include <hip/hip_runtime.h>
#include <math.h>

#define B 8
#define S 4096
#define H 2048
#define VOC 32
#define LSYM 8
#define EMB 64

// ---------------- Kernel 1: partial pooling over S ----------------
// grid: (H/1024, B, split), block: 256. Each thread owns 4 consecutive h (float4).
__global__ __launch_bounds__(256) void pool_partial(const float* __restrict__ hid,
                                                    float* __restrict__ part,
                                                    int chunk) {
    const int hb = blockIdx.x;          // which 1024-wide h chunk
    const int b  = blockIdx.y;
    const int sp = blockIdx.z;
    const int t  = threadIdx.x;
    const int h4 = hb * 1024 + t * 4;
    float4 acc = {0.f, 0.f, 0.f, 0.f};
    const float* base = hid + (size_t)b * S * H + h4;
    const int s0 = sp * chunk;
    for (int s = 0; s < chunk; ++s) {
        const float4 v = *reinterpret_cast<const float4*>(base + (size_t)(s0 + s) * H);
        acc.x += v.x; acc.y += v.y; acc.z += v.z; acc.w += v.w;
    }
    *reinterpret_cast<float4*>(part + ((size_t)sp * B + b) * H + h4) = acc;
}

// ---------------- Kernel 2: reduce partials -> pooled mean ----------------
__global__ __launch_bounds__(256) void pool_reduce(const float* __restrict__ part,
                                                   float* __restrict__ pooled,
                                                   int split) {
    const int i4 = blockIdx.x * 256 + threadIdx.x;   // over B*H/4
    if (i4 >= B * H / 4) return;
    float4 acc = {0.f, 0.f, 0.f, 0.f};
    for (int sp = 0; sp < split; ++sp) {
        const float4 v = *reinterpret_cast<const float4*>(part + (size_t)sp * B * H + (size_t)i4 * 4);
        acc.x += v.x; acc.y += v.y; acc.z += v.z; acc.w += v.w;
    }
    const float inv = 1.0f / (float)S;
    acc.x *= inv; acc.y *= inv; acc.z *= inv; acc.w *= inv;
    *reinterpret_cast<float4*>(pooled + (size_t)i4 * 4) = acc;
}

// ---------------- Kernel 3: fused tiny MLP pipeline ----------------
// grid = B blocks, 256 threads each.
__device__ __forceinline__ float block_sum256(float x, float* red) {
    const int t = threadIdx.x;
    red[t] = x;
    __syncthreads();
    for (int s = 128; s > 0; s >>= 1) {
        if (t < s) red[t] += red[t + s];
        __syncthreads();
    }
    const float r = red[0];
    __syncthreads();
    return r;
}

__global__ __launch_bounds__(256) void mlp_fused(
    const float* __restrict__ pooled, const float* __restrict__ gu,
    const float* __restrict__ ew1, const float* __restrict__ eb1,
    const float* __restrict__ g1,  const float* __restrict__ bb1,
    const float* __restrict__ ew2, const float* __restrict__ eb2,
    const float* __restrict__ emb_tab,
    const float* __restrict__ dw1, const float* __restrict__ db1,
    const float* __restrict__ g2,  const float* __restrict__ bb2,
    const float* __restrict__ dw2, const float* __restrict__ db2,
    float* __restrict__ dec_scaled) {
    __shared__ float ps[H];            // pooled row, 8 KB
    __shared__ float red[256];
    __shared__ float hs[256];
    __shared__ float es[LSYM * EMB];   // 512 floats

    const int b = blockIdx.x;
    const int t = threadIdx.x;

    for (int i = t; i < H; i += 256) ps[i] = pooled[b * H + i];
    __syncthreads();

    // ---- encoder layer 1: h1[t] = pooled . ew1[t,:] + eb1[t]
    float acc = eb1[t];
    {
        const float* wrow = ew1 + (size_t)t * H;
        for (int k = 0; k < H; k += 4) {
            const float4 w = *reinterpret_cast<const float4*>(wrow + k);
            acc += w.x * ps[k] + w.y * ps[k + 1] + w.z * ps[k + 2] + w.w * ps[k + 3];
        }
    }
    // ---- LN1 + exact GELU
    {
        const float m = block_sum256(acc, red) * (1.0f / 256.0f);
        const float d = acc - m;
        const float v = block_sum256(d * d, red) * (1.0f / 256.0f);
        float x = d * rsqrtf(v + 1e-5f) * g1[t] + bb1[t];
        x = 0.5f * x * (1.0f + erff(x * 0.70710678118654752f));
        hs[t] = x;
    }
    __syncthreads();

    // ---- encoder layer 2: logits + gumbel noise
    float z;
    {
        float a2 = eb2[t];
        const float* w2row = ew2 + t * 256;
        for (int k = 0; k < 256; k += 4) {
            const float4 w = *reinterpret_cast<const float4*>(w2row + k);
            a2 += w.x * hs[k] + w.y * hs[k + 1] + w.z * hs[k + 2] + w.w * hs[k + 3];
        }
        const float u = gu[b * 256 + t];
        z = a2 - logf(-logf(u));   // (logits + g) / TAU, TAU = 1
    }

    // ---- per-l argmax over V=32 within a 32-lane group (first-max tiebreak)
    {
        int   bi = t & 31;
        float bz = z;
        for (int off = 16; off; off >>= 1) {
            const float oz = __shfl_xor(bz, off, 32);
            const int   oi = __shfl_xor(bi, off, 32);
            if (oz > bz || (oz == bz && oi < bi)) { bz = oz; bi = oi; }
        }
        // soft_symbols == one_hot(argmax) numerically -> gather embedding row
        const int l = t >> 5, v32 = t & 31;
        es[l * EMB + v32]      = emb_tab[bi * EMB + v32];
        es[l * EMB + 32 + v32] = emb_tab[bi * EMB + 32 + v32];
    }
    __syncthreads();

    // ---- decoder layer 1
    float a3 = db1[t];
    {
        const float* d1row = dw1 + t * (LSYM * EMB);
        for (int k = 0; k < LSYM * EMB; k += 4) {
            const float4 w = *reinterpret_cast<const float4*>(d1row + k);
            a3 += w.x * es[k] + w.y * es[k + 1] + w.z * es[k + 2] + w.w * es[k + 3];
        }
    }
    // ---- LN2 + exact GELU
    {
        const float m2 = block_sum256(a3, red) * (1.0f / 256.0f);
        const float dd = a3 - m2;
        const float vv = block_sum256(dd * dd, red) * (1.0f / 256.0f);
        float y = dd * rsqrtf(vv + 1e-5f) * g2[t] + bb2[t];
        y = 0.5f * y * (1.0f + erff(y * 0.70710678118654752f));
        hs[t] = y;   // safe: all reads of previous hs happened before LN2's barriers
    }
    __syncthreads();

    // ---- decoder layer 2 -> decoded, pre-scaled by 0.1
    for (int j = t; j < H; j += 256) {
        float a4 = db2[j];
        const float* d2row = dw2 + (size_t)j * 256;
        for (int k = 0; k < 256; k += 4) {
            const float4 w = *reinterpret_cast<const float4*>(d2row + k);
            a4 += w.x * hs[k] + w.y * hs[k + 1] + w.z * hs[k + 2] + w.w * hs[k + 3];
        }
        dec_scaled[b * H + j] = 0.1f * a4;
    }
}

// ---------------- Kernel 4: residual broadcast add ----------------
__global__ __launch_bounds__(256) void residual_add(const float* __restrict__ hid,
                                                    const float* __restrict__ dec,
                                                    float* __restrict__ out,
                                                    size_t n4) {
    size_t i = (size_t)blockIdx.x * blockDim.x + threadIdx.x;
    const size_t stride = (size_t)gridDim.x * blockDim.x;
    const float4* __restrict__ hv4 = reinterpret_cast<const float4*>(hid);
    const float4* __restrict__ dv4 = reinterpret_cast<const float4*>(dec);
    float4* __restrict__ ov4 = reinterpret_cast<float4*>(out);
    for (; i < n4; i += stride) {
        const float4 hv = hv4[i];
        const size_t b  = i >> 21;            // / (S*H/4 = 2^21)
        const size_t h4 = i & (H / 4 - 1);    // & 511
        const float4 dv = dv4[b * (H / 4) + h4];
        float4 o;
        o.x = hv.x + dv.x; o.y = hv.y + dv.y; o.z = hv.z + dv.z; o.w = hv.w + dv.w;
        ov4[i] = o;
    }
}

extern "C" void kernel_launch(void* const* d_in, const int* in_sizes, int n_in,
                              void* d_out, int out_size, void* d_ws, size_t ws_size,
                              hipStream_t stream) {
    const float* hid   = (const float*)d_in[0];
    const float* gu    = (const float*)d_in[1];
    const float* ew1   = (const float*)d_in[2];
    const float* eb1   = (const float*)d_in[3];
    const float* g1    = (const float*)d_in[4];
    const float* bb1   = (const float*)d_in[5];
    const float* ew2   = (const float*)d_in[6];
    const float* eb2   = (const float*)d_in[7];
    const float* emb   = (const float*)d_in[8];
    const float* dw1   = (const float*)d_in[9];
    const float* db1   = (const float*)d_in[10];
    const float* g2    = (const float*)d_in[11];
    const float* bb2   = (const float*)d_in[12];
    const float* dw2   = (const float*)d_in[13];
    const float* db2   = (const float*)d_in[14];
    float* out = (float*)d_out;

    // workspace layout: [ partials: split*B*H | pooled: B*H | dec_scaled: B*H ]
    const size_t avail_floats = ws_size / 4;
    int split = 64;
    while (split > 1 && (size_t)(split + 2) * B * H > avail_floats) split >>= 1;
    const int chunk = S / split;

    float* part    = (float*)d_ws;
    float* pooled  = part + (size_t)split * B * H;
    float* dec_sc  = pooled + (size_t)B * H;

    pool_partial<<<dim3(H / 1024, B, split), 256, 0, stream>>>(hid, part, chunk);
    pool_reduce<<<(B * H / 4 + 255) / 256, 256, 0, stream>>>(part, pooled, split);
    mlp_fused<<<B, 256, 0, stream>>>(pooled, gu, ew1, eb1, g1, bb1, ew2, eb2, emb,
                                     dw1, db1, g2, bb2, dw2, db2, dec_sc);
    const size_t n4 = (size_t)B * S * H / 4;
    residual_add<<<2048, 256, 0, stream>>>(hid, dec_sc, out, n4);
}

// Round 2
// 215.555 us; speedup vs baseline: 1.5849x; 1.5849x over previous
//
#include <hip/hip_runtime.h>
#include <math.h>

#define B 8
#define S 4096
#define H 2048
#define VOC 32
#define LSYM 8
#define EMB 64

// ---------------- Kernel 1: partial pooling over S ----------------
__global__ __launch_bounds__(256) void pool_partial(const float* __restrict__ hid,
                                                    float* __restrict__ part,
                                                    int chunk) {
    const int hb = blockIdx.x;
    const int b  = blockIdx.y;
    const int sp = blockIdx.z;
    const int t  = threadIdx.x;
    const int h4 = hb * 1024 + t * 4;
    float4 acc = {0.f, 0.f, 0.f, 0.f};
    const float* base = hid + (size_t)b * S * H + h4;
    const int s0 = sp * chunk;
    for (int s = 0; s < chunk; ++s) {
        const float4 v = *reinterpret_cast<const float4*>(base + (size_t)(s0 + s) * H);
        acc.x += v.x; acc.y += v.y; acc.z += v.z; acc.w += v.w;
    }
    *reinterpret_cast<float4*>(part + ((size_t)sp * B + b) * H + h4) = acc;
}

// ---------------- Kernel 2: reduce partials -> pooled mean ----------------
__global__ __launch_bounds__(256) void pool_reduce(const float* __restrict__ part,
                                                   float* __restrict__ pooled,
                                                   int split) {
    const int i4 = blockIdx.x * 256 + threadIdx.x;
    if (i4 >= B * H / 4) return;
    float4 acc = {0.f, 0.f, 0.f, 0.f};
    for (int sp = 0; sp < split; ++sp) {
        const float4 v = *reinterpret_cast<const float4*>(part + (size_t)sp * B * H + (size_t)i4 * 4);
        acc.x += v.x; acc.y += v.y; acc.z += v.z; acc.w += v.w;
    }
    const float inv = 1.0f / (float)S;
    acc.x *= inv; acc.y *= inv; acc.z *= inv; acc.w *= inv;
    *reinterpret_cast<float4*>(pooled + (size_t)i4 * 4) = acc;
}

// ---------------- Kernel 3a: enc layer 1 matvec, one wave per output ----------------
// out1[b][t] = pooled[b] . ew1[t] + eb1[t];  B*256 = 2048 waves -> 512 blocks
__global__ __launch_bounds__(256) void enc1_matvec(const float* __restrict__ pooled,
                                                   const float* __restrict__ ew1,
                                                   const float* __restrict__ eb1,
                                                   float* __restrict__ out1) {
    const int wv   = (blockIdx.x * 256 + threadIdx.x) >> 6;
    const int lane = threadIdx.x & 63;
    const int b = wv >> 8, t = wv & 255;
    const float4* wrow = reinterpret_cast<const float4*>(ew1 + (size_t)t * H);
    const float4* prow = reinterpret_cast<const float4*>(pooled + b * H);
    float acc = 0.f;
#pragma unroll
    for (int i = 0; i < 8; ++i) {
        const float4 w = wrow[lane + 64 * i];
        const float4 p = prow[lane + 64 * i];
        acc += w.x * p.x + w.y * p.y + w.z * p.z + w.w * p.w;
    }
    for (int off = 32; off; off >>= 1) acc += __shfl_xor(acc, off, 64);
    if (lane == 0) out1[b * 256 + t] = acc + eb1[t];
}

// ---------------- Kernel 3b: middle (LN1+GELU+enc2+gumbel+embed+dec1+LN2+GELU) ----------------
__device__ __forceinline__ float block_sum256(float x, float* red) {
    const int t = threadIdx.x;
    red[t] = x;
    __syncthreads();
    for (int s = 128; s > 0; s >>= 1) {
        if (t < s) red[t] += red[t + s];
        __syncthreads();
    }
    const float r = red[0];
    __syncthreads();
    return r;
}

__global__ __launch_bounds__(256) void mlp_middle(
    const float* __restrict__ out1, const float* __restrict__ gu,
    const float* __restrict__ g1,  const float* __restrict__ bb1,
    const float* __restrict__ ew2, const float* __restrict__ eb2,
    const float* __restrict__ emb_tab,
    const float* __restrict__ dw1, const float* __restrict__ db1,
    const float* __restrict__ g2,  const float* __restrict__ bb2,
    float* __restrict__ hs2) {
    __shared__ float red[256];
    __shared__ float hs[256];
    __shared__ float es[LSYM * EMB];

    const int b = blockIdx.x;
    const int t = threadIdx.x;

    float acc = out1[b * 256 + t];
    // ---- LN1 + exact GELU
    {
        const float m = block_sum256(acc, red) * (1.0f / 256.0f);
        const float d = acc - m;
        const float v = block_sum256(d * d, red) * (1.0f / 256.0f);
        float x = d * rsqrtf(v + 1e-5f) * g1[t] + bb1[t];
        x = 0.5f * x * (1.0f + erff(x * 0.70710678118654752f));
        hs[t] = x;
    }
    __syncthreads();

    // ---- encoder layer 2: logits + gumbel noise
    float z;
    {
        float a2 = eb2[t];
        const float* w2row = ew2 + t * 256;
        for (int k = 0; k < 256; k += 4) {
            const float4 w = *reinterpret_cast<const float4*>(w2row + k);
            a2 += w.x * hs[k] + w.y * hs[k + 1] + w.z * hs[k + 2] + w.w * hs[k + 3];
        }
        const float u = gu[b * 256 + t];
        z = a2 - logf(-logf(u));
    }

    // ---- per-l argmax over V=32 (first-max tiebreak) + embedding gather
    {
        int   bi = t & 31;
        float bz = z;
        for (int off = 16; off; off >>= 1) {
            const float oz = __shfl_xor(bz, off, 32);
            const int   oi = __shfl_xor(bi, off, 32);
            if (oz > bz || (oz == bz && oi < bi)) { bz = oz; bi = oi; }
        }
        const int l = t >> 5, v32 = t & 31;
        es[l * EMB + v32]      = emb_tab[bi * EMB + v32];
        es[l * EMB + 32 + v32] = emb_tab[bi * EMB + 32 + v32];
    }
    __syncthreads();

    // ---- decoder layer 1
    float a3 = db1[t];
    {
        const float* d1row = dw1 + t * (LSYM * EMB);
        for (int k = 0; k < LSYM * EMB; k += 4) {
            const float4 w = *reinterpret_cast<const float4*>(d1row + k);
            a3 += w.x * es[k] + w.y * es[k + 1] + w.z * es[k + 2] + w.w * es[k + 3];
        }
    }
    // ---- LN2 + exact GELU -> hs2 (global, tiny)
    {
        const float m2 = block_sum256(a3, red) * (1.0f / 256.0f);
        const float dd = a3 - m2;
        const float vv = block_sum256(dd * dd, red) * (1.0f / 256.0f);
        float y = dd * rsqrtf(vv + 1e-5f) * g2[t] + bb2[t];
        y = 0.5f * y * (1.0f + erff(y * 0.70710678118654752f));
        hs2[b * 256 + t] = y;
    }
}

// ---------------- Kernel 3c: dec layer 2 matvec, one wave per output ----------------
// dec_sc[b][j] = 0.1*(hs2[b] . dw2[j] + db2[j]);  B*2048 = 16384 waves -> 4096 blocks
__global__ __launch_bounds__(256) void dec2_matvec(const float* __restrict__ hs2,
                                                   const float* __restrict__ dw2,
                                                   const float* __restrict__ db2,
                                                   float* __restrict__ dec_sc) {
    const int wv   = (blockIdx.x * 256 + threadIdx.x) >> 6;
    const int lane = threadIdx.x & 63;
    const int b = wv >> 11, j = wv & 2047;
    const float4 w = reinterpret_cast<const float4*>(dw2 + (size_t)j * 256)[lane];
    const float4 h = reinterpret_cast<const float4*>(hs2 + b * 256)[lane];
    float acc = w.x * h.x + w.y * h.y + w.z * h.z + w.w * h.w;
    for (int off = 32; off; off >>= 1) acc += __shfl_xor(acc, off, 64);
    if (lane == 0) dec_sc[b * 2048 + j] = 0.1f * (acc + db2[j]);
}

// ---------------- Kernel 4: residual broadcast add ----------------
__global__ __launch_bounds__(256) void residual_add(const float* __restrict__ hid,
                                                    const float* __restrict__ dec,
                                                    float* __restrict__ out,
                                                    size_t n4) {
    size_t i = (size_t)blockIdx.x * blockDim.x + threadIdx.x;
    const size_t stride = (size_t)gridDim.x * blockDim.x;
    const float4* __restrict__ hv4 = reinterpret_cast<const float4*>(hid);
    const float4* __restrict__ dv4 = reinterpret_cast<const float4*>(dec);
    float4* __restrict__ ov4 = reinterpret_cast<float4*>(out);
    for (; i < n4; i += stride) {
        const float4 hv = hv4[i];
        const size_t b  = i >> 21;
        const size_t h4 = i & (H / 4 - 1);
        const float4 dv = dv4[b * (H / 4) + h4];
        float4 o;
        o.x = hv.x + dv.x; o.y = hv.y + dv.y; o.z = hv.z + dv.z; o.w = hv.w + dv.w;
        ov4[i] = o;
    }
}

extern "C" void kernel_launch(void* const* d_in, const int* in_sizes, int n_in,
                              void* d_out, int out_size, void* d_ws, size_t ws_size,
                              hipStream_t stream) {
    const float* hid   = (const float*)d_in[0];
    const float* gu    = (const float*)d_in[1];
    const float* ew1   = (const float*)d_in[2];
    const float* eb1   = (const float*)d_in[3];
    const float* g1    = (const float*)d_in[4];
    const float* bb1   = (const float*)d_in[5];
    const float* ew2   = (const float*)d_in[6];
    const float* eb2   = (const float*)d_in[7];
    const float* emb   = (const float*)d_in[8];
    const float* dw1   = (const float*)d_in[9];
    const float* db1   = (const float*)d_in[10];
    const float* g2    = (const float*)d_in[11];
    const float* bb2   = (const float*)d_in[12];
    const float* dw2   = (const float*)d_in[13];
    const float* db2   = (const float*)d_in[14];
    float* out = (float*)d_out;

    // workspace layout: [ part: split*B*H | pooled: B*H | dec_sc: B*H | out1: B*256 | hs2: B*256 ]
    const size_t avail_floats = ws_size / 4;
    int split = 64;
    while (split > 1 && (size_t)(split + 3) * B * H > avail_floats) split >>= 1;
    const int chunk = S / split;

    float* part   = (float*)d_ws;
    float* pooled = part + (size_t)split * B * H;
    float* dec_sc = pooled + (size_t)B * H;
    float* out1   = dec_sc + (size_t)B * H;
    float* hs2    = out1 + (size_t)B * 256;

    pool_partial<<<dim3(H / 1024, B, split), 256, 0, stream>>>(hid, part, chunk);
    pool_reduce<<<(B * H / 4 + 255) / 256, 256, 0, stream>>>(part, pooled, split);
    enc1_matvec<<<B * 256 / 4, 256, 0, stream>>>(pooled, ew1, eb1, out1);
    mlp_middle<<<B, 256, 0, stream>>>(out1, gu, g1, bb1, ew2, eb2, emb,
                                      dw1, db1, g2, bb2, hs2);
    dec2_matvec<<<B * 2048 / 4, 256, 0, stream>>>(hs2, dw2, db2, dec_sc);
    const size_t n4 = (size_t)B * S * H / 4;
    residual_add<<<2048, 256, 0, stream>>>(hid, dec_sc, out, n4);
}